// Round 3
// baseline (163.285 us; speedup 1.0000x reference)
//
#include <hip/hip_runtime.h>
#include <hip/hip_bf16.h>

#define B_    8
#define H_    8
#define L_    1024
#define D_    32
#define C_    256
#define NK    64
#define PSTR  72

typedef __attribute__((ext_vector_type(8))) short bf16x8;
typedef __attribute__((ext_vector_type(4))) float f32x4;

__device__ inline unsigned short f2bf(float f) {   // RNE f32 -> bf16
    union { float f; unsigned int u; } x; x.f = f;
    return (unsigned short)((x.u + 0x7fffu + ((x.u >> 16) & 1u)) >> 16);
}

__device__ inline unsigned int pk_bf16(float lo, float hi) {  // packed RNE cvt
    union { __hip_bfloat162 h; unsigned int u; } c;
    c.h = __float22bfloat162_rn(make_float2(lo, hi));
    return c.u;
}

// ---------------------------------------------------------------------------
// Pre-pass: K (f32) -> bf16 flat copy; V (f32) -> V^T bf16 [b][h][d][L].
// blocks 0..1023: K convert (2048 elems each). blocks 1024..2047: V transpose
// via f32 LDS tile, stride 65 dwords (65 % 32 == 1 -> conflict-free both ways).
// ---------------------------------------------------------------------------
__global__ __launch_bounds__(256) void prep_kv(
    const float* __restrict__ k, const float* __restrict__ v,
    unsigned short* __restrict__ kbf, unsigned short* __restrict__ vt)
{
    const int tid = threadIdx.x;
    const int blk = blockIdx.x;
    __shared__ float sTf[32][65];

    if (blk < 1024) {
        const size_t base = (size_t)blk * 2048 + (size_t)tid * 8;
        float4 f0 = ((const float4*)(k + base))[0];
        float4 f1 = ((const float4*)(k + base))[1];
        uint4 o;
        o.x = pk_bf16(f0.x, f0.y);
        o.y = pk_bf16(f0.z, f0.w);
        o.z = pk_bf16(f1.x, f1.y);
        o.w = pk_bf16(f1.z, f1.w);
        *(uint4*)(kbf + base) = o;
    } else {
        const int bid = blk - 1024;
        const int bh = bid >> 4, g = bid & 15;   // 64 (b,h) x 16 key-groups
        const int b = bh >> 3, h = bh & 7;
        {   // load 64 keys x 32 dims, scatter into sTf[d][key] (2-way max)
            const int key = tid >> 2, d8 = (tid & 3) * 8;
            const float* src = v + ((size_t)(b * L_ + g * 64 + key) * C_ + h * D_ + d8);
            float4 a = ((const float4*)src)[0];
            float4 c = ((const float4*)src)[1];
            sTf[d8 + 0][key] = a.x; sTf[d8 + 1][key] = a.y;
            sTf[d8 + 2][key] = a.z; sTf[d8 + 3][key] = a.w;
            sTf[d8 + 4][key] = c.x; sTf[d8 + 5][key] = c.y;
            sTf[d8 + 6][key] = c.z; sTf[d8 + 7][key] = c.w;
        }
        __syncthreads();
        {   // read rows of sTf (scalar dwords, 2-way max), cvt, 16B store
            const int d = tid >> 3, seg = tid & 7;
            uint4 o;
            o.x = pk_bf16(sTf[d][seg * 8 + 0], sTf[d][seg * 8 + 1]);
            o.y = pk_bf16(sTf[d][seg * 8 + 2], sTf[d][seg * 8 + 3]);
            o.z = pk_bf16(sTf[d][seg * 8 + 4], sTf[d][seg * 8 + 5]);
            o.w = pk_bf16(sTf[d][seg * 8 + 6], sTf[d][seg * 8 + 7]);
            *(uint4*)(vt + ((size_t)(bh * D_ + d) * L_ + g * 64 + seg * 8)) = o;
        }
    }
}

// ---------------------------------------------------------------------------
// Main: 128 threads = 2 waves, each wave owns 16 q-rows. grid 2048.
// blk = h*256 + (b*32 + qt): stride-256 head swizzle -> all 8 heads of a
// (b,qt) land on the same XCD (256 % 8 == 0) -> bias tile read once per XCD.
// K/V fragments come straight from global (bf16, pre-passed). Only LDS: the
// per-wave P strip (wave-local, no barrier in the K-loop) + mask row.
// ---------------------------------------------------------------------------
__global__ __launch_bounds__(128, 4) void attn_main(
    const float* __restrict__ q,
    const float* __restrict__ v,
    const int*   __restrict__ mask,
    const float* __restrict__ bias,
    const unsigned short* __restrict__ kbf,
    const unsigned short* __restrict__ vt,
    float*       __restrict__ out)
{
    __shared__ float sMadd[L_];
    __shared__ __align__(16) unsigned short sP[2][16][PSTR];

    const int tid  = threadIdx.x;
    const int wv   = tid >> 6;
    const int ln   = tid & 63;
    const int l16  = ln & 15;
    const int quad = ln >> 4;

    const int blk = blockIdx.x;
    const int h   = blk >> 8;
    const int rem = blk & 255;
    const int b   = rem >> 5;
    const int qt  = rem & 31;
    const int q0  = qt * 32 + wv * 16;

    const float scale = 0.17677669529663687f; // 1/sqrt(32)

    // ---- stage mask -> additive floats for the whole batch row (once) ----
    {
        const int4* mp = (const int4*)(mask + b * L_);
        int4 m0 = mp[tid * 2], m1 = mp[tid * 2 + 1];
        float* dst = &sMadd[tid * 8];
        dst[0] = m0.x ? 0.f : -1e9f;
        dst[1] = m0.y ? 0.f : -1e9f;
        dst[2] = m0.z ? 0.f : -1e9f;
        dst[3] = m0.w ? 0.f : -1e9f;
        dst[4] = m1.x ? 0.f : -1e9f;
        dst[5] = m1.y ? 0.f : -1e9f;
        dst[6] = m1.z ? 0.f : -1e9f;
        dst[7] = m1.w ? 0.f : -1e9f;
    }
    __syncthreads();

    // ---- Q A-fragment straight from f32 global (loop-invariant) ----
    bf16x8 qfrag;
    {
        const float* qp = q + ((size_t)(b * L_ + q0 + l16) * C_ + h * D_ + quad * 8);
        float4 a = ((const float4*)qp)[0];
        float4 c = ((const float4*)qp)[1];
        __align__(16) unsigned int u[4] = {
            pk_bf16(a.x, a.y), pk_bf16(a.z, a.w),
            pk_bf16(c.x, c.y), pk_bf16(c.z, c.w)};
        qfrag = *(const bf16x8*)u;
    }

    f32x4 Oacc[2] = {{0.f,0.f,0.f,0.f},{0.f,0.f,0.f,0.f}};
    float psum[4] = {0.f, 0.f, 0.f, 0.f};

    const unsigned short* kbase = kbf + ((size_t)(b * L_) * C_ + h * D_ + quad * 8);
    const unsigned short* vbase = vt + ((size_t)((b * H_ + h) * D_) * L_);
    const size_t brow0 = (size_t)(b * L_ + q0 + quad * 4) * L_;

    for (int j0 = 0; j0 < L_; j0 += NK) {
        // ---- K B-fragments: 4 x 16B global loads (L2-resident) ----
        bf16x8 kf[4];
#pragma unroll
        for (int nt = 0; nt < 4; ++nt)
            kf[nt] = *(const bf16x8*)(kbase + (size_t)(j0 + nt * 16 + l16) * C_);

        f32x4 S[4];
#pragma unroll
        for (int nt = 0; nt < 4; ++nt)
            S[nt] = __builtin_amdgcn_mfma_f32_16x16x32_bf16(
                qfrag, kf[nt], (f32x4){0.f,0.f,0.f,0.f}, 0, 0, 0);

        float madd[4];
#pragma unroll
        for (int nt = 0; nt < 4; ++nt)
            madd[nt] = sMadd[j0 + nt * 16 + l16];

        // ---- bias + mask + exp (C-layout: col=l16+16nt, row=quad*4+r) ----
#pragma unroll
        for (int nt = 0; nt < 4; ++nt) {
#pragma unroll
            for (int r = 0; r < 4; ++r) {
                float t = bias[brow0 + (size_t)r * L_ + j0 + nt * 16 + l16] + madd[nt];
                float s = fmaf(S[nt][r], scale, t);
                float p = __expf(s);          // masked key: exp(-1e9) == 0
                psum[r] += p;                 // per-lane; reduced in epilogue
                S[nt][r] = p;
            }
        }

        // ---- P -> bf16 (packed cvt) -> this wave's LDS strip ----
#pragma unroll
        for (int nt = 0; nt < 4; ++nt) {
#pragma unroll
            for (int r = 0; r < 4; r += 2) {
                unsigned int u = pk_bf16(S[nt][r], S[nt][r + 1]);
                sP[wv][quad * 4 + r    ][nt * 16 + l16] = (unsigned short)u;
                sP[wv][quad * 4 + r + 1][nt * 16 + l16] = (unsigned short)(u >> 16);
            }
        }

        // ---- PV: A=P (wave-local LDS), B=V^T (global, L2-resident) ----
#pragma unroll
        for (int s2 = 0; s2 < 2; ++s2) {
            bf16x8 pf = *(const bf16x8*)&sP[wv][l16][s2 * 32 + quad * 8];
#pragma unroll
            for (int nt = 0; nt < 2; ++nt) {
                bf16x8 vf = *(const bf16x8*)(vbase + (size_t)(nt * 16 + l16) * L_
                                             + j0 + s2 * 32 + quad * 8);
                Oacc[nt] = __builtin_amdgcn_mfma_f32_16x16x32_bf16(pf, vf, Oacc[nt], 0, 0, 0);
            }
        }
    }

    // ---- epilogue: deferred row-sum reduction, normalize or pass-through ----
#pragma unroll
    for (int r = 0; r < 4; ++r) {
        float t = psum[r];
        t += __shfl_xor(t, 1);
        t += __shfl_xor(t, 2);
        t += __shfl_xor(t, 4);
        t += __shfl_xor(t, 8);
        const int qrow = q0 + quad * 4 + r;
        const float inv = 1.f / t;
        const bool active = (sMadd[qrow] == 0.f);
        const size_t base = (size_t)(b * L_ + qrow) * C_ + h * D_;
#pragma unroll
        for (int nt = 0; nt < 2; ++nt) {
            const size_t idx = base + nt * 16 + l16;
            out[idx] = active ? Oacc[nt][r] * inv : v[idx];
        }
    }
}

// ---------------------------------------------------------------------------
// Round-2 kernel kept as fallback if ws_size < 8 MB (proven correct).
// ---------------------------------------------------------------------------
#define MQ    64
#define KSTR  48
#define VSTR  72

__global__ __launch_bounds__(256) void masked_attn_mfma(
    const float* __restrict__ q,
    const float* __restrict__ k,
    const float* __restrict__ v,
    const int*   __restrict__ mask,
    const float* __restrict__ bias,
    float*       __restrict__ out)
{
    __shared__ __align__(16) unsigned short sQ[MQ][KSTR];
    __shared__ __align__(16) unsigned short sK[NK][KSTR];
    __shared__ __align__(16) unsigned short sVt[D_][VSTR];
    __shared__ __align__(16) unsigned short sP2[4][16][VSTR];
    __shared__ float sMadd2[NK];

    const int tid  = threadIdx.x;
    const int wv   = tid >> 6;
    const int ln   = tid & 63;
    const int l16  = ln & 15;
    const int quad = ln >> 4;

    const int blk = blockIdx.x;
    const int h   = blk & 7;
    const int qt  = (blk >> 3) & 15;
    const int b   = blk >> 7;
    const int q0  = qt * MQ;

    const float scale = 0.17677669529663687f;

    {
        const int row = tid >> 2, d0 = (tid & 3) * 8;
        const float* src = q + ((size_t)(b * L_ + q0 + row) * C_ + h * D_ + d0);
        float4 a = ((const float4*)src)[0];
        float4 c = ((const float4*)src)[1];
        __align__(16) unsigned short t8[8] = {
            f2bf(a.x), f2bf(a.y), f2bf(a.z), f2bf(a.w),
            f2bf(c.x), f2bf(c.y), f2bf(c.z), f2bf(c.w)};
        *(int4*)&sQ[row][d0] = *(const int4*)t8;
    }
    __syncthreads();

    const bf16x8 qfrag = *(const bf16x8*)&sQ[wv * 16 + l16][quad * 8];

    f32x4 Oacc[2] = {{0.f,0.f,0.f,0.f},{0.f,0.f,0.f,0.f}};
    float lsum[4] = {0.f, 0.f, 0.f, 0.f};

    for (int j0 = 0; j0 < L_; j0 += NK) {
        __syncthreads();
        {
            const int row = tid >> 2, d0 = (tid & 3) * 8;
            const size_t src = (size_t)(b * L_ + j0 + row) * C_ + h * D_ + d0;
            float4 ka = ((const float4*)(k + src))[0];
            float4 kb = ((const float4*)(k + src))[1];
            __align__(16) unsigned short t8[8] = {
                f2bf(ka.x), f2bf(ka.y), f2bf(ka.z), f2bf(ka.w),
                f2bf(kb.x), f2bf(kb.y), f2bf(kb.z), f2bf(kb.w)};
            *(int4*)&sK[row][d0] = *(const int4*)t8;

            float4 va = ((const float4*)(v + src))[0];
            float4 vb = ((const float4*)(v + src))[1];
            sVt[d0 + 0][row] = f2bf(va.x);
            sVt[d0 + 1][row] = f2bf(va.y);
            sVt[d0 + 2][row] = f2bf(va.z);
            sVt[d0 + 3][row] = f2bf(va.w);
            sVt[d0 + 4][row] = f2bf(vb.x);
            sVt[d0 + 5][row] = f2bf(vb.y);
            sVt[d0 + 6][row] = f2bf(vb.z);
            sVt[d0 + 7][row] = f2bf(vb.w);
            if (tid < NK) sMadd2[tid] = mask[b * L_ + j0 + tid] ? 0.f : -1e9f;
        }
        __syncthreads();

        bf16x8 kf[4];
#pragma unroll
        for (int nt = 0; nt < 4; ++nt)
            kf[nt] = *(const bf16x8*)&sK[nt * 16 + l16][quad * 8];

        f32x4 S[4];
#pragma unroll
        for (int nt = 0; nt < 4; ++nt)
            S[nt] = __builtin_amdgcn_mfma_f32_16x16x32_bf16(
                qfrag, kf[nt], (f32x4){0.f,0.f,0.f,0.f}, 0, 0, 0);

        float psum[4] = {0.f, 0.f, 0.f, 0.f};
        const size_t brow0 = (size_t)(b * L_ + q0 + wv * 16 + quad * 4) * L_ + j0;
#pragma unroll
        for (int nt = 0; nt < 4; ++nt) {
            const float madd = sMadd2[nt * 16 + l16];
#pragma unroll
            for (int r = 0; r < 4; ++r) {
                float s = S[nt][r] * scale + bias[brow0 + (size_t)r * L_ + nt * 16 + l16] + madd;
                float p = __expf(s);
                psum[r] += p;
                S[nt][r] = p;
            }
        }

#pragma unroll
        for (int nt = 0; nt < 4; ++nt)
#pragma unroll
            for (int r = 0; r < 4; ++r)
                sP2[wv][quad * 4 + r][nt * 16 + l16] = f2bf(S[nt][r]);

#pragma unroll
        for (int r = 0; r < 4; ++r) {
            float t = psum[r];
            t += __shfl_xor(t, 1);
            t += __shfl_xor(t, 2);
            t += __shfl_xor(t, 4);
            t += __shfl_xor(t, 8);
            lsum[r] += t;
        }

#pragma unroll
        for (int s2 = 0; s2 < 2; ++s2) {
            bf16x8 pf = *(const bf16x8*)&sP2[wv][l16][s2 * 32 + quad * 8];
#pragma unroll
            for (int nt = 0; nt < 2; ++nt) {
                bf16x8 vf = *(const bf16x8*)&sVt[nt * 16 + l16][s2 * 32 + quad * 8];
                Oacc[nt] = __builtin_amdgcn_mfma_f32_16x16x32_bf16(pf, vf, Oacc[nt], 0, 0, 0);
            }
        }
    }

#pragma unroll
    for (int r = 0; r < 4; ++r) {
        const int qg = q0 + wv * 16 + quad * 4 + r;
        const int active = mask[b * L_ + qg];
        const size_t obase = (size_t)(b * L_ + qg) * C_ + h * D_;
        const float inv = 1.f / lsum[r];
#pragma unroll
        for (int nt = 0; nt < 2; ++nt) {
            float val;
            if (active) val = Oacc[nt][r] * inv;
            else        val = v[obase + nt * 16 + l16];
            out[obase + nt * 16 + l16] = val;
        }
    }
}

extern "C" void kernel_launch(void* const* d_in, const int* in_sizes, int n_in,
                              void* d_out, int out_size, void* d_ws, size_t ws_size,
                              hipStream_t stream) {
    const float* q    = (const float*)d_in[0];
    const float* k    = (const float*)d_in[1];
    const float* v    = (const float*)d_in[2];
    const int*   mask = (const int*)d_in[3];
    const float* bias = (const float*)d_in[4];
    float* out = (float*)d_out;

    if (ws_size >= (size_t)8 * 1024 * 1024) {
        unsigned short* kbf = (unsigned short*)d_ws;
        unsigned short* vt  = kbf + (size_t)2 * 1024 * 1024;  // 4 MB in
        prep_kv<<<2048, 256, 0, stream>>>(k, v, kbf, vt);
        attn_main<<<2048, 128, 0, stream>>>(q, v, mask, bias, kbf, vt, out);
    } else {
        masked_attn_mfma<<<1024, 256, 0, stream>>>(q, k, v, mask, bias, out);
    }
}

// Round 4
// 124.840 us; speedup vs baseline: 1.3080x; 1.3080x over previous
//
#include <hip/hip_runtime.h>
#include <hip/hip_bf16.h>

#define B_    8
#define H_    8
#define L_    1024
#define D_    32
#define C_    256
#define NK    64
#define PSTR  72

typedef __attribute__((ext_vector_type(8))) short bf16x8;
typedef __attribute__((ext_vector_type(4))) float f32x4;

__device__ inline unsigned short f2bf(float f) {
    union { float f; unsigned int u; } x; x.f = f;
    return (unsigned short)((x.u + 0x7fffu + ((x.u >> 16) & 1u)) >> 16);
}

__device__ inline unsigned int pk_bf16(float lo, float hi) {
    union { __hip_bfloat162 h; unsigned int u; } c;
    c.h = __float22bfloat162_rn(make_float2(lo, hi));
    return c.u;
}

// ---------------------------------------------------------------------------
// Prep: K f32 [b][key][h][d] -> bf16 kbf [b][h][key][d]  (blocks 0..1023)
//       V f32 -> V^T bf16 vt [bh][chunk][d][key], XOR-swizzled 16B atoms:
//       atom' = atom ^ (d&7), so unpadded LDS frag reads are conflict-free.
//       (blocks 1024..2047)
// ---------------------------------------------------------------------------
__global__ __launch_bounds__(256) void prep_kv(
    const float* __restrict__ k, const float* __restrict__ v,
    unsigned short* __restrict__ kbf, unsigned short* __restrict__ vt)
{
    const int tid = threadIdx.x;
    const int blk = blockIdx.x;
    __shared__ float sTf[32][65];

    if (blk < 1024) {
        const size_t g = (size_t)blk * 2048 + (size_t)tid * 8;   // elem in K
        const int b   = (int)(g >> 18);
        const int r1  = (int)(g & 262143);
        const int key = r1 >> 8;
        const int h   = (r1 >> 5) & 7;
        const int d0  = r1 & 31;
        float4 f0 = ((const float4*)(k + g))[0];
        float4 f1 = ((const float4*)(k + g))[1];
        uint4 o;
        o.x = pk_bf16(f0.x, f0.y);
        o.y = pk_bf16(f0.z, f0.w);
        o.z = pk_bf16(f1.x, f1.y);
        o.w = pk_bf16(f1.z, f1.w);
        *(uint4*)(kbf + ((size_t)((b * 8 + h) * 1024 + key) * 32 + d0)) = o;
    } else {
        const int bid = blk - 1024;
        const int bh = bid >> 4, c = bid & 15;     // 64 (b,h) x 16 chunks
        const int b = bh >> 3, h = bh & 7;
        {   // load 64 keys x 32 dims -> f32 transpose tile (stride 65: no conflicts)
            const int row = tid >> 2, d8 = (tid & 3) * 8;
            const float* src = v + ((size_t)(b * L_ + c * 64 + row) * C_ + h * D_ + d8);
            float4 a = ((const float4*)src)[0];
            float4 cc = ((const float4*)src)[1];
            sTf[d8 + 0][row] = a.x;  sTf[d8 + 1][row] = a.y;
            sTf[d8 + 2][row] = a.z;  sTf[d8 + 3][row] = a.w;
            sTf[d8 + 4][row] = cc.x; sTf[d8 + 5][row] = cc.y;
            sTf[d8 + 6][row] = cc.z; sTf[d8 + 7][row] = cc.w;
        }
        __syncthreads();
        {   // rows of sTf -> bf16, write swizzled atom
            const int d = tid >> 3, seg = tid & 7;
            uint4 o;
            o.x = pk_bf16(sTf[d][seg * 8 + 0], sTf[d][seg * 8 + 1]);
            o.y = pk_bf16(sTf[d][seg * 8 + 2], sTf[d][seg * 8 + 3]);
            o.z = pk_bf16(sTf[d][seg * 8 + 4], sTf[d][seg * 8 + 5]);
            o.w = pk_bf16(sTf[d][seg * 8 + 6], sTf[d][seg * 8 + 7]);
            const int ap = seg ^ (d & 7);
            *(uint4*)(vt + ((size_t)((bh * 16 + c) * 32 + d) * 64 + ap * 8)) = o;
        }
    }
}

// ---------------------------------------------------------------------------
// Main: 256 thr = 4 waves, MQ=64 q-rows per block, grid 1024 (4/CU, all
// co-resident). h = blk>>7 so all 8 heads of a (b,qt) share an XCD (bias L2
// reuse, verified round 3). Per-chunk staging: ONE uint4 K + ONE uint4 V per
// thread from prep'd contiguous tiles, double-buffered in registers across
// the single per-chunk barrier.
// ---------------------------------------------------------------------------
__global__ __launch_bounds__(256, 4) void attn_main(
    const float* __restrict__ q,
    const float* __restrict__ v,
    const int*   __restrict__ mask,
    const float* __restrict__ bias,
    const unsigned short* __restrict__ kbf,
    const unsigned short* __restrict__ vt,
    float*       __restrict__ out)
{
    __shared__ __align__(16) unsigned short sK[2][NK * D_];   // 4 KB each
    __shared__ __align__(16) unsigned short sV[2][D_ * NK];   // 4 KB each, swizzled
    __shared__ float sMadd[L_];                                // 4 KB
    __shared__ __align__(16) unsigned short sP[4][16][PSTR];   // 9 KB

    const int tid  = threadIdx.x;
    const int wv   = tid >> 6;
    const int ln   = tid & 63;
    const int l16  = ln & 15;
    const int quad = ln >> 4;

    const int blk = blockIdx.x;
    const int h   = blk >> 7;
    const int rem = blk & 127;
    const int b   = rem >> 4;
    const int qt  = rem & 15;
    const int q0  = qt * 64 + wv * 16;
    const int bh  = b * H_ + h;

    const float scale = 0.17677669529663687f; // 1/sqrt(32)

    // ---- mask -> additive floats, whole batch row (once) ----
    {
        int4 m = ((const int4*)(mask + b * L_))[tid];
        sMadd[tid * 4 + 0] = m.x ? 0.f : -1e9f;
        sMadd[tid * 4 + 1] = m.y ? 0.f : -1e9f;
        sMadd[tid * 4 + 2] = m.z ? 0.f : -1e9f;
        sMadd[tid * 4 + 3] = m.w ? 0.f : -1e9f;
    }

    // ---- Q A-fragment from f32 global (loop-invariant) ----
    bf16x8 qfrag;
    {
        const float* qp = q + ((size_t)(b * L_ + q0 + l16) * C_ + h * D_ + quad * 8);
        float4 a = ((const float4*)qp)[0];
        float4 c = ((const float4*)qp)[1];
        __align__(16) unsigned int u[4] = {
            pk_bf16(a.x, a.y), pk_bf16(a.z, a.w),
            pk_bf16(c.x, c.y), pk_bf16(c.z, c.w)};
        qfrag = *(const bf16x8*)u;
    }

    const unsigned short* kt  = kbf + (size_t)bh * L_ * D_;      // chunk stride 2048 elems
    const unsigned short* vtb = vt  + (size_t)bh * 16 * D_ * NK; // chunk stride 2048 elems

    // ---- prologue: stage chunk 0 ----
    uint4 kreg = *(const uint4*)(kt  + tid * 8);
    uint4 vreg = *(const uint4*)(vtb + tid * 8);
    *(uint4*)(&sK[0][tid * 8]) = kreg;
    *(uint4*)(&sV[0][tid * 8]) = vreg;
    __syncthreads();

    f32x4 Oacc[2] = {{0.f,0.f,0.f,0.f},{0.f,0.f,0.f,0.f}};
    float psum[4] = {0.f, 0.f, 0.f, 0.f};
    const size_t brow0 = (size_t)(b * L_ + q0 + quad * 4) * L_;

    for (int c = 0; c < 16; ++c) {
        const int cur = c & 1;
        const int j0  = c * NK;

        // ---- prefetch next chunk's tiles into registers (global, async) ----
        if (c < 15) {
            kreg = *(const uint4*)(kt  + (c + 1) * 2048 + tid * 8);
            vreg = *(const uint4*)(vtb + (c + 1) * 2048 + tid * 8);
        }

        // ---- bias loads issued early (consumed after QK^T) ----
        float bz[4][4];
#pragma unroll
        for (int nt = 0; nt < 4; ++nt)
#pragma unroll
            for (int r = 0; r < 4; ++r)
                bz[nt][r] = bias[brow0 + (size_t)r * L_ + j0 + nt * 16 + l16];

        // ---- QK^T ----
        bf16x8 kf[4];
#pragma unroll
        for (int nt = 0; nt < 4; ++nt)
            kf[nt] = *(const bf16x8*)&sK[cur][(nt * 16 + l16) * D_ + quad * 8];

        f32x4 S[4];
#pragma unroll
        for (int nt = 0; nt < 4; ++nt)
            S[nt] = __builtin_amdgcn_mfma_f32_16x16x32_bf16(
                qfrag, kf[nt], (f32x4){0.f,0.f,0.f,0.f}, 0, 0, 0);

        float madd[4];
#pragma unroll
        for (int nt = 0; nt < 4; ++nt)
            madd[nt] = sMadd[j0 + nt * 16 + l16];

        // ---- bias + mask + exp ----
#pragma unroll
        for (int nt = 0; nt < 4; ++nt) {
#pragma unroll
            for (int r = 0; r < 4; ++r) {
                float t = bz[nt][r] + madd[nt];
                float p = __expf(fmaf(S[nt][r], scale, t));  // masked: exp(-1e9)==0
                psum[r] += p;
                S[nt][r] = p;
            }
        }

        // ---- P -> bf16 -> this wave's LDS strip (wave-local, no barrier) ----
#pragma unroll
        for (int nt = 0; nt < 4; ++nt) {
#pragma unroll
            for (int r = 0; r < 4; r += 2) {
                unsigned int u = pk_bf16(S[nt][r], S[nt][r + 1]);
                sP[wv][quad * 4 + r    ][nt * 16 + l16] = (unsigned short)u;
                sP[wv][quad * 4 + r + 1][nt * 16 + l16] = (unsigned short)(u >> 16);
            }
        }

        // ---- PV (V^T frags from swizzled LDS) ----
#pragma unroll
        for (int s2 = 0; s2 < 2; ++s2) {
            bf16x8 pf = *(const bf16x8*)&sP[wv][l16][s2 * 32 + quad * 8];
#pragma unroll
            for (int nt = 0; nt < 2; ++nt) {
                const int d  = nt * 16 + l16;
                const int ap = (s2 * 4 + quad) ^ (l16 & 7);
                bf16x8 vf = *(const bf16x8*)&sV[cur][d * NK + ap * 8];
                Oacc[nt] = __builtin_amdgcn_mfma_f32_16x16x32_bf16(pf, vf, Oacc[nt], 0, 0, 0);
            }
        }

        // ---- commit prefetched tiles, single barrier per chunk ----
        if (c < 15) {
            *(uint4*)(&sK[cur ^ 1][tid * 8]) = kreg;
            *(uint4*)(&sV[cur ^ 1][tid * 8]) = vreg;
            __syncthreads();
        }
    }

    // ---- epilogue ----
#pragma unroll
    for (int r = 0; r < 4; ++r) {
        float t = psum[r];
        t += __shfl_xor(t, 1);
        t += __shfl_xor(t, 2);
        t += __shfl_xor(t, 4);
        t += __shfl_xor(t, 8);
        const int qrow = q0 + quad * 4 + r;
        const float inv = 1.f / t;
        const bool active = (sMadd[qrow] == 0.f);
        const size_t base = (size_t)(b * L_ + qrow) * C_ + h * D_;
#pragma unroll
        for (int nt = 0; nt < 2; ++nt) {
            const size_t idx = base + nt * 16 + l16;
            out[idx] = active ? Oacc[nt][r] * inv : v[idx];
        }
    }
}

// ---------------------------------------------------------------------------
// Round-2 fallback if ws_size < 8 MB (proven correct).
// ---------------------------------------------------------------------------
#define MQ    64
#define KSTR  48
#define VSTR  72

__global__ __launch_bounds__(256) void masked_attn_mfma(
    const float* __restrict__ q,
    const float* __restrict__ k,
    const float* __restrict__ v,
    const int*   __restrict__ mask,
    const float* __restrict__ bias,
    float*       __restrict__ out)
{
    __shared__ __align__(16) unsigned short sQ[MQ][KSTR];
    __shared__ __align__(16) unsigned short sKt[NK][KSTR];
    __shared__ __align__(16) unsigned short sVt[D_][VSTR];
    __shared__ __align__(16) unsigned short sP2[4][16][VSTR];
    __shared__ float sMadd2[NK];

    const int tid  = threadIdx.x;
    const int wv   = tid >> 6;
    const int ln   = tid & 63;
    const int l16  = ln & 15;
    const int quad = ln >> 4;

    const int blk = blockIdx.x;
    const int h   = blk & 7;
    const int qt  = (blk >> 3) & 15;
    const int b   = blk >> 7;
    const int q0  = qt * MQ;
    const float scale = 0.17677669529663687f;

    {
        const int row = tid >> 2, d0 = (tid & 3) * 8;
        const float* src = q + ((size_t)(b * L_ + q0 + row) * C_ + h * D_ + d0);
        float4 a = ((const float4*)src)[0];
        float4 c = ((const float4*)src)[1];
        __align__(16) unsigned short t8[8] = {
            f2bf(a.x), f2bf(a.y), f2bf(a.z), f2bf(a.w),
            f2bf(c.x), f2bf(c.y), f2bf(c.z), f2bf(c.w)};
        *(int4*)&sQ[row][d0] = *(const int4*)t8;
    }
    __syncthreads();

    const bf16x8 qfrag = *(const bf16x8*)&sQ[wv * 16 + l16][quad * 8];
    f32x4 Oacc[2] = {{0.f,0.f,0.f,0.f},{0.f,0.f,0.f,0.f}};
    float lsum[4] = {0.f, 0.f, 0.f, 0.f};

    for (int j0 = 0; j0 < L_; j0 += NK) {
        __syncthreads();
        {
            const int row = tid >> 2, d0 = (tid & 3) * 8;
            const size_t src = (size_t)(b * L_ + j0 + row) * C_ + h * D_ + d0;
            float4 ka = ((const float4*)(k + src))[0];
            float4 kb = ((const float4*)(k + src))[1];
            __align__(16) unsigned short t8[8] = {
                f2bf(ka.x), f2bf(ka.y), f2bf(ka.z), f2bf(ka.w),
                f2bf(kb.x), f2bf(kb.y), f2bf(kb.z), f2bf(kb.w)};
            *(int4*)&sKt[row][d0] = *(const int4*)t8;

            float4 va = ((const float4*)(v + src))[0];
            float4 vb = ((const float4*)(v + src))[1];
            sVt[d0 + 0][row] = f2bf(va.x);
            sVt[d0 + 1][row] = f2bf(va.y);
            sVt[d0 + 2][row] = f2bf(va.z);
            sVt[d0 + 3][row] = f2bf(va.w);
            sVt[d0 + 4][row] = f2bf(vb.x);
            sVt[d0 + 5][row] = f2bf(vb.y);
            sVt[d0 + 6][row] = f2bf(vb.z);
            sVt[d0 + 7][row] = f2bf(vb.w);
            if (tid < NK) sMadd2[tid] = mask[b * L_ + j0 + tid] ? 0.f : -1e9f;
        }
        __syncthreads();

        bf16x8 kf[4];
#pragma unroll
        for (int nt = 0; nt < 4; ++nt)
            kf[nt] = *(const bf16x8*)&sKt[nt * 16 + l16][quad * 8];

        f32x4 S[4];
#pragma unroll
        for (int nt = 0; nt < 4; ++nt)
            S[nt] = __builtin_amdgcn_mfma_f32_16x16x32_bf16(
                qfrag, kf[nt], (f32x4){0.f,0.f,0.f,0.f}, 0, 0, 0);

        float psum[4] = {0.f, 0.f, 0.f, 0.f};
        const size_t brow0 = (size_t)(b * L_ + q0 + wv * 16 + quad * 4) * L_ + j0;
#pragma unroll
        for (int nt = 0; nt < 4; ++nt) {
            const float madd = sMadd2[nt * 16 + l16];
#pragma unroll
            for (int r = 0; r < 4; ++r) {
                float s = S[nt][r] * scale + bias[brow0 + (size_t)r * L_ + nt * 16 + l16] + madd;
                float p = __expf(s);
                psum[r] += p;
                S[nt][r] = p;
            }
        }
#pragma unroll
        for (int nt = 0; nt < 4; ++nt)
#pragma unroll
            for (int r = 0; r < 4; ++r)
                sP2[wv][quad * 4 + r][nt * 16 + l16] = f2bf(S[nt][r]);
#pragma unroll
        for (int r = 0; r < 4; ++r) {
            float t = psum[r];
            t += __shfl_xor(t, 1);
            t += __shfl_xor(t, 2);
            t += __shfl_xor(t, 4);
            t += __shfl_xor(t, 8);
            lsum[r] += t;
        }
#pragma unroll
        for (int s2 = 0; s2 < 2; ++s2) {
            bf16x8 pf = *(const bf16x8*)&sP2[wv][l16][s2 * 32 + quad * 8];
#pragma unroll
            for (int nt = 0; nt < 2; ++nt) {
                bf16x8 vf = *(const bf16x8*)&sVt[nt * 16 + l16][s2 * 32 + quad * 8];
                Oacc[nt] = __builtin_amdgcn_mfma_f32_16x16x32_bf16(pf, vf, Oacc[nt], 0, 0, 0);
            }
        }
    }
#pragma unroll
    for (int r = 0; r < 4; ++r) {
        const int qg = q0 + wv * 16 + quad * 4 + r;
        const int active = mask[b * L_ + qg];
        const size_t obase = (size_t)(b * L_ + qg) * C_ + h * D_;
        const float inv = 1.f / lsum[r];
#pragma unroll
        for (int nt = 0; nt < 2; ++nt) {
            float val;
            if (active) val = Oacc[nt][r] * inv;
            else        val = v[obase + nt * 16 + l16];
            out[obase + nt * 16 + l16] = val;
        }
    }
}

extern "C" void kernel_launch(void* const* d_in, const int* in_sizes, int n_in,
                              void* d_out, int out_size, void* d_ws, size_t ws_size,
                              hipStream_t stream) {
    const float* q    = (const float*)d_in[0];
    const float* k    = (const float*)d_in[1];
    const float* v    = (const float*)d_in[2];
    const int*   mask = (const int*)d_in[3];
    const float* bias = (const float*)d_in[4];
    float* out = (float*)d_out;

    if (ws_size >= (size_t)8 * 1024 * 1024) {
        unsigned short* kbf = (unsigned short*)d_ws;
        unsigned short* vt  = kbf + (size_t)2 * 1024 * 1024;  // 4 MB in
        prep_kv<<<2048, 256, 0, stream>>>(k, v, kbf, vt);
        attn_main<<<1024, 256, 0, stream>>>(q, v, mask, bias, kbf, vt, out);
    } else {
        masked_attn_mfma<<<1024, 256, 0, stream>>>(q, k, v, mask, bias, out);
    }
}